// Round 3
// baseline (18547.923 us; speedup 1.0000x reference)
//
#include <hip/hip_runtime.h>

#define BB 64
#define NN 128
#define DD 512
#define NBLK 128
#define NTHR 512
#define CPB 24          // weight cols per block (x-class and mgate-class)
#define WSTRIDE 1032    // u16 stride per LDS weight col: [Wh 512 | Wl 512 | pad 8]

typedef unsigned short u16;
typedef __attribute__((ext_vector_type(8))) __bf16 bf16x8;
typedef __attribute__((ext_vector_type(4))) float f32x4;

__device__ __forceinline__ float b2f(u16 u) {
    union { unsigned int i; float f; } c; c.i = ((unsigned int)u) << 16; return c.f;
}
__device__ __forceinline__ u16 f2b(float f) {
    union { float f; unsigned int i; } c; c.f = f;
    return (u16)((c.i + 0x7FFFu + ((c.i >> 16) & 1u)) >> 16);
}
__device__ __forceinline__ float sigm(float x) { return 1.f / (1.f + __expf(-x)); }
__device__ __forceinline__ float tanh_(float x) {
    x = fminf(fmaxf(x, -15.f), 15.f);
    float e = __expf(2.f * x);
    return (e - 1.f) / (e + 1.f);
}

// device-scope grid barrier
__device__ __forceinline__ void gbar(int* ctr, int target) {
    __syncthreads();
    if (threadIdx.x == 0) {
        __hip_atomic_fetch_add(ctr, 1, __ATOMIC_ACQ_REL, __HIP_MEMORY_SCOPE_AGENT);
        while (__hip_atomic_load(ctr, __ATOMIC_ACQUIRE, __HIP_MEMORY_SCOPE_AGENT) < target) {
            __builtin_amdgcn_s_sleep(2);
        }
    }
    __syncthreads();
}

// 64rows x 16cols GEMM tile pair (waves 0,1), K=512 with hi/lo 3-term.
// A: ablob rows of 1024 u16 [Ah(512)|Al(512)] ; W: block's LDS 24-col blob.
__device__ __forceinline__ void gemm24(
    const u16* __restrict__ ablob, const u16* __restrict__ wlds,
    const float* __restrict__ biasA, const float* __restrict__ biasB,
    float* __restrict__ bc, int outoff, int blk, int wv, int lr, int lq)
{
    if (wv >= 2) return;
    const int coff = wv * 8;                 // tiles [0..15] and [8..23] (overlap benign)
    const int col = blk * CPB + coff + lr;
    const u16* wcol = wlds + (coff + lr) * WSTRIDE;
    f32x4 acc[4] = {{0,0,0,0},{0,0,0,0},{0,0,0,0},{0,0,0,0}};
    for (int c = 0; c < 16; ++c) {
        const int kb = c * 32 + lq * 8;
        bf16x8 wh = *(const bf16x8*)(wcol + kb);
        bf16x8 wl = *(const bf16x8*)(wcol + 512 + kb);
        #pragma unroll
        for (int rt = 0; rt < 4; ++rt) {
            const u16* ar = ablob + (rt * 16 + lr) * 1024 + kb;
            bf16x8 ah = *(const bf16x8*)(ar);
            bf16x8 al = *(const bf16x8*)(ar + 512);
            acc[rt] = __builtin_amdgcn_mfma_f32_16x16x32_bf16(ah, wh, acc[rt], 0, 0, 0);
            acc[rt] = __builtin_amdgcn_mfma_f32_16x16x32_bf16(al, wh, acc[rt], 0, 0, 0);
            acc[rt] = __builtin_amdgcn_mfma_f32_16x16x32_bf16(ah, wl, acc[rt], 0, 0, 0);
        }
    }
    float bias = (col < 1536) ? biasA[col] : biasB[col - 1536];
    #pragma unroll
    for (int rt = 0; rt < 4; ++rt) {
        #pragma unroll
        for (int r = 0; r < 4; ++r) {
            int row = rt * 16 + lq * 4 + r;
            bc[row * 6656 + outoff + col] = acc[rt][r] + bias;
        }
    }
}

// elementwise GRU-combine for row j>=1.
// bcb: [0,512) M | [512,2048) gh_c | [2048,3584) gi_p | [3584,5120) gi_c | [5120,6656) gh_p
__device__ __forceinline__ void ew_row(
    int b, int j, const float* feat, const float* bcb, const float* lin_w,
    float* H, float* out, float* hk, float* s_red)
{
    const int t = threadIdx.x, d = t;
    float Mv  = bcb[d];
    float ir  = bcb[3584 + d], iz = bcb[4096 + d], inn = bcb[4608 + d];
    float hr  = bcb[512 + d],  hz = bcb[1024 + d], hn  = bcb[1536 + d];
    float r = sigm(ir + hr), z = sigm(iz + hz);
    float nv = tanh_(inn + r * hn);
    float C = (1.f - z) * nv + z * Mv;
    float gir = bcb[2048 + d], giz = bcb[2560 + d], gin = bcb[3072 + d];
    float ghr = bcb[5120 + d], ghz = bcb[5632 + d], ghn = bcb[6144 + d];
    float r2 = sigm(gir + ghr), z2 = sigm(giz + ghz);
    float n2 = tanh_(gin + r2 * ghn);
    float x = feat[(b * NN + j) * DD + d];
    float P = (1.f - z2) * n2 + z2 * x;
    float Hv = C + P;
    H[(b * NN + j) * DD + d] = Hv;
    out[(b * NN + j) * DD + d] = Hv;
    s_red[t] = Hv * lin_w[DD + d];
    __syncthreads();
    if (t < 256) s_red[t] += s_red[t + 256];
    __syncthreads();
    if (t < 128) s_red[t] += s_red[t + 128];
    __syncthreads();
    if (t < 64) {
        float p = s_red[t] + s_red[t + 64];
        #pragma unroll
        for (int off = 32; off; off >>= 1) p += __shfl_down(p, off, 64);
        if (t == 0) hk[b * NN + j] = p;
    }
    __syncthreads();
}

__global__ __launch_bounds__(NTHR) void grn_kernel(
    const float* feat, const float* Wi_c, const float* Wh_c, const float* bi_c, const float* bh_c,
    const float* Wi_p, const float* Wh_p, const float* bi_p, const float* bh_p,
    const float* lin_w, const float* lin_b, const float* Wr0, const float* Wr1,
    const int* adj, const int* smask,
    float* out,
    float* H, float* hk, float* q, u16* ublob, u16* mblob, u16* xblob, float* bc,
    u16* WrB, int* ctr)
{
    const int t = threadIdx.x, blk = blockIdx.x;
    const int lane = t & 63, wv = t >> 6;
    const int lr = lane & 15, lq = lane >> 4;
    int gen = 0;

    __shared__ u16 s_wx[CPB * WSTRIDE];      // x-class weights (Wi_c|Wh_p), 49.5 KB
    __shared__ u16 s_wm[CPB * WSTRIDE];      // mgate weights (Wh_c|Wi_p), 49.5 KB
    __shared__ float s_red[NTHR];
    __shared__ __align__(16) float s_pu[4][128][4];
    __shared__ __align__(16) float s_pt[4][128][4];
    __shared__ float s_w[NN], s_ws[NN];

    // ===== Ph0: LDS weight split, WrB blob, q, xblob row 0 =====
    {
        for (int cc = 0; cc < CPB; ++cc) {
            int j = blk * CPB + cc;
            const float* sx = (j < 1536) ? (Wi_c + j * DD) : (Wh_p + (j - 1536) * DD);
            float wx = sx[t];
            u16 hx = f2b(wx);
            s_wx[cc * WSTRIDE + t] = hx;
            s_wx[cc * WSTRIDE + 512 + t] = f2b(wx - b2f(hx));
            const float* sm = (j < 1536) ? (Wh_c + j * DD) : (Wi_p + (j - 1536) * DD);
            float wm = sm[t];
            u16 hm = f2b(wm);
            s_wm[cc * WSTRIDE + t] = hm;
            s_wm[cc * WSTRIDE + 512 + t] = f2b(wm - b2f(hm));
        }
        // WrB: 512 cols x [W0h|W0l|W1h|W1l] (2048 u16)
        for (int cc = 0; cc < 4; ++cc) {
            int c = blk * 4 + cc;
            float w0 = Wr0[c * DD + t], w1 = Wr1[c * DD + t];
            u16 h0 = f2b(w0), h1 = f2b(w1);
            WrB[c * 2048 + t] = h0;
            WrB[c * 2048 + 512 + t] = f2b(w0 - b2f(h0));
            WrB[c * 2048 + 1024 + t] = h1;
            WrB[c * 2048 + 1536 + t] = f2b(w1 - b2f(h1));
        }
        // q[b,n]
        {
            float linb = lin_b[0];
            float wqf[8];
            #pragma unroll
            for (int jj = 0; jj < 8; ++jj) wqf[jj] = lin_w[lane * 8 + jj];
            for (int rr = 0; rr < 8; ++rr) {
                int row = blk * 64 + wv * 8 + rr;
                const float* fp = feat + row * DD + lane * 8;
                float p = 0.f;
                #pragma unroll
                for (int jj = 0; jj < 8; ++jj) p += fp[jj] * wqf[jj];
                #pragma unroll
                for (int off = 32; off; off >>= 1) p += __shfl_down(p, off, 64);
                if (lane == 0) q[row] = p + linb;
            }
        }
        // xblob row 0
        if (blk < BB) {
            float x = feat[(blk * NN + 0) * DD + t];
            u16 h = f2b(x);
            xblob[blk * 1024 + t] = h;
            xblob[blk * 1024 + 512 + t] = f2b(x - b2f(h));
        }
    }
    gbar(ctr, ++gen * NBLK);

    // ===== Ph0x: x-gates for row 0 =====
    gemm24(xblob, s_wx, bi_c, bh_p, bc, 3584, blk, wv, lr, lq);
    gbar(ctr, ++gen * NBLK);

    // ===== Ph1: row 0 init =====
    if (blk < BB) {
        int b = blk, d = t;
        const float* bcb = bc + b * 6656;
        float ir = bcb[3584 + d], iz = bcb[4096 + d], inn = bcb[4608 + d];
        float r = sigm(ir + bh_c[d]), z = sigm(iz + bh_c[512 + d]);
        float nv = tanh_(inn + r * bh_c[1024 + d]);
        float C = (1.f - z) * nv;
        float ghr = bcb[5120 + d], ghz = bcb[5632 + d], ghn = bcb[6144 + d];
        float r2 = sigm(bi_p[d] + ghr), z2 = sigm(bi_p[512 + d] + ghz);
        float n2 = tanh_(bi_p[1024 + d] + r2 * ghn);
        float x = feat[(b * NN + 0) * DD + d];
        float P = (1.f - z2) * n2 + z2 * x;
        float Hv = C + P;
        H[(b * NN + 0) * DD + d] = Hv;
        out[(b * NN + 0) * DD + d] = Hv;
        s_red[t] = Hv * lin_w[DD + d];
        __syncthreads();
        if (t < 256) s_red[t] += s_red[t + 256];
        __syncthreads();
        if (t < 128) s_red[t] += s_red[t + 128];
        __syncthreads();
        if (t < 64) {
            float p = s_red[t] + s_red[t + 64];
            #pragma unroll
            for (int off = 32; off; off >>= 1) p += __shfl_down(p, off, 64);
            if (t == 0) hk[b * NN + 0] = p;
        }
    }
    gbar(ctr, ++gen * NBLK);

    // ===== main scan =====
    for (int i = 1; i < NN; ++i) {
        // ---- PhA ----
        if (blk < BB) {
            int b = blk;
            if (i >= 2) ew_row(b, i - 1, feat, bc + b * 6656, lin_w, H, out, hk, s_red);
            // xblob row i
            {
                float x = feat[(b * NN + i) * DD + t];
                u16 h = f2b(x);
                xblob[b * 1024 + t] = h;
                xblob[b * 1024 + 512 + t] = f2b(x - b2f(h));
            }
            // softmax (wave 0)
            if (wv == 0) {
                float qv = q[b * NN + i];
                const int* arow = adj + (b * NN + i) * NN;
                const int* srow = smask + (b * NN + i) * NN;
                int n2 = lane + 64;
                float a0 = -1e30f, a1 = -1e30f;
                if (lane < i && arow[lane] != 0) a0 = qv + hk[b * NN + lane];
                if (n2 < i && arow[n2] != 0) a1 = qv + hk[b * NN + n2];
                float m = fmaxf(a0, a1);
                #pragma unroll
                for (int off = 32; off; off >>= 1) m = fmaxf(m, __shfl_xor(m, off, 64));
                float e0 = __expf(a0 - m), e1 = __expf(a1 - m);
                float ss = e0 + e1;
                #pragma unroll
                for (int off = 32; off; off >>= 1) ss += __shfl_xor(ss, off, 64);
                float inv = 1.f / ss;
                float w0 = e0 * inv, w1 = e1 * inv;
                s_w[lane] = w0; s_w[n2] = w1;
                s_ws[lane] = w0 * (float)srow[lane];
                s_ws[n2] = w1 * (float)srow[n2];
            }
            __syncthreads();
            // H-scan: 4 row-groups x float4
            {
                int g = t >> 7, dq = t & 127;
                f32x4 u0 = {0, 0, 0, 0}, ut = {0, 0, 0, 0};
                const float* Hb = H + b * NN * DD;
                for (int n = g; n < i; n += 4) {
                    f32x4 h = *(const f32x4*)(Hb + n * DD + dq * 4);
                    float ws_ = s_ws[n], w_ = s_w[n];
                    u0 += ws_ * h;
                    ut += w_ * h;
                }
                *(f32x4*)&s_pu[g][dq][0] = u0;
                *(f32x4*)&s_pt[g][dq][0] = ut;
            }
            __syncthreads();
            if (t < 128) {
                int dq = t;
                f32x4 U0 = *(const f32x4*)&s_pu[0][dq][0];
                f32x4 UT = *(const f32x4*)&s_pt[0][dq][0];
                #pragma unroll
                for (int g = 1; g < 4; ++g) {
                    U0 += *(const f32x4*)&s_pu[g][dq][0];
                    UT += *(const f32x4*)&s_pt[g][dq][0];
                }
                #pragma unroll
                for (int e = 0; e < 4; ++e) {
                    int d = dq * 4 + e;
                    float a0 = U0[e], a1 = UT[e] - U0[e];
                    u16 h0 = f2b(a0);
                    ublob[b * 2048 + d] = h0;
                    ublob[b * 2048 + 512 + d] = f2b(a0 - b2f(h0));
                    u16 h1 = f2b(a1);
                    ublob[b * 2048 + 1024 + d] = h1;
                    ublob[b * 2048 + 1536 + d] = f2b(a1 - b2f(h1));
                }
            }
        }
        gbar(ctr, ++gen * NBLK);

        // ---- PhB: x-gates (waves 0,1) + M-GEMM (blk<32, wave 2) ----
        gemm24(xblob, s_wx, bi_c, bh_p, bc, 3584, blk, wv, lr, lq);
        if (blk < 32 && wv == 2) {
            int c0 = blk * 16;
            int colw = c0 + lr;
            const u16* wcol = WrB + colw * 2048;
            f32x4 acc[4] = {{0,0,0,0},{0,0,0,0},{0,0,0,0},{0,0,0,0}};
            for (int s = 0; s < 2; ++s) {
                for (int c = 0; c < 16; ++c) {
                    int kb = s * 1024 + c * 32 + lq * 8;
                    bf16x8 wh = *(const bf16x8*)(wcol + kb);
                    bf16x8 wl = *(const bf16x8*)(wcol + 512 + kb);
                    #pragma unroll
                    for (int rt = 0; rt < 4; ++rt) {
                        const u16* ar = ublob + (rt * 16 + lr) * 2048 + kb;
                        bf16x8 ah = *(const bf16x8*)(ar);
                        bf16x8 al = *(const bf16x8*)(ar + 512);
                        acc[rt] = __builtin_amdgcn_mfma_f32_16x16x32_bf16(ah, wh, acc[rt], 0, 0, 0);
                        acc[rt] = __builtin_amdgcn_mfma_f32_16x16x32_bf16(al, wh, acc[rt], 0, 0, 0);
                        acc[rt] = __builtin_amdgcn_mfma_f32_16x16x32_bf16(ah, wl, acc[rt], 0, 0, 0);
                    }
                }
            }
            #pragma unroll
            for (int rt = 0; rt < 4; ++rt) {
                #pragma unroll
                for (int r = 0; r < 4; ++r) {
                    int row = rt * 16 + lq * 4 + r;
                    float v = acc[rt][r];
                    bc[row * 6656 + colw] = v;
                    u16 h = f2b(v);
                    mblob[row * 1024 + colw] = h;
                    mblob[row * 1024 + 512 + colw] = f2b(v - b2f(h));
                }
            }
        }
        gbar(ctr, ++gen * NBLK);

        // ---- PhC: M-gates ----
        gemm24(mblob, s_wm, bh_c, bi_p, bc, 512, blk, wv, lr, lq);
        gbar(ctr, ++gen * NBLK);
    }

    // ---- final row 127 ----
    if (blk < BB) {
        ew_row(blk, NN - 1, feat, bc + blk * 6656, lin_w, H, out, hk, s_red);
    }
}

extern "C" void kernel_launch(void* const* d_in, const int* in_sizes, int n_in,
                              void* d_out, int out_size, void* d_ws, size_t ws_size,
                              hipStream_t stream) {
    const float* feat = (const float*)d_in[0];
    const float* Wi_c = (const float*)d_in[1];
    const float* Wh_c = (const float*)d_in[2];
    const float* bi_c = (const float*)d_in[3];
    const float* bh_c = (const float*)d_in[4];
    const float* Wi_p = (const float*)d_in[5];
    const float* Wh_p = (const float*)d_in[6];
    const float* bi_p = (const float*)d_in[7];
    const float* bh_p = (const float*)d_in[8];
    const float* lin_w = (const float*)d_in[9];
    const float* lin_b = (const float*)d_in[10];
    const float* Wr0 = (const float*)d_in[11];
    const float* Wr1 = (const float*)d_in[12];
    const int* adj = (const int*)d_in[13];
    const int* smask = (const int*)d_in[14];
    float* out = (float*)d_out;

    char* ws = (char*)d_ws;
    size_t off = 0;
    int* ctr = (int*)(ws + off);    off += 256;
    float* H = (float*)(ws + off);  off += (size_t)BB * NN * DD * 4;   // 16.8 MB
    float* hk = (float*)(ws + off); off += (size_t)BB * NN * 4;
    float* q = (float*)(ws + off);  off += (size_t)BB * NN * 4;
    u16* ublob = (u16*)(ws + off);  off += (size_t)BB * 2048 * 2;      // 256 KB
    u16* mblob = (u16*)(ws + off);  off += (size_t)BB * 1024 * 2;      // 128 KB
    u16* xblob = (u16*)(ws + off);  off += (size_t)BB * 1024 * 2;      // 128 KB
    float* bc = (float*)(ws + off); off += (size_t)BB * 6656 * 4;      // 1.7 MB
    u16* WrB = (u16*)(ws + off);    off += (size_t)512 * 2048 * 2;     // 2 MB

    hipMemsetAsync(d_ws, 0, 256, stream);
    hipLaunchKernelGGL(grn_kernel, dim3(NBLK), dim3(NTHR), 0, stream,
                       feat, Wi_c, Wh_c, bi_c, bh_c, Wi_p, Wh_p, bi_p, bh_p,
                       lin_w, lin_b, Wr0, Wr1, adj, smask, out,
                       H, hk, q, ublob, mblob, xblob, bc, WrB, ctr);
}

// Round 5
// 6393.238 us; speedup vs baseline: 2.9012x; 2.9012x over previous
//
#include <hip/hip_runtime.h>

#define BB 64
#define NN 128
#define DD 512
#define NBLK 128
#define NTHR 512
#define GCOLS 24
#define WCS 2056   // u16 per combined-weight col: [Wh 1024 | Wl 1024 | pad 8]
#define WXS 1032   // u16 per x-weight col: [Wh 512 | Wl 512 | pad 8]
#define BCS 6656

typedef unsigned short u16;
typedef __attribute__((ext_vector_type(8))) __bf16 bf16x8;
typedef __attribute__((ext_vector_type(4))) float f32x4;

#define MFMA16(a, b, c) __builtin_amdgcn_mfma_f32_16x16x32_bf16((a), (b), (c), 0, 0, 0)

__device__ __forceinline__ float b2f(u16 u) {
    union { unsigned int i; float f; } c; c.i = ((unsigned int)u) << 16; return c.f;
}
__device__ __forceinline__ u16 f2b(float f) {
    union { float f; unsigned int i; } c; c.f = f;
    return (u16)((c.i + 0x7FFFu + ((c.i >> 16) & 1u)) >> 16);
}
__device__ __forceinline__ float sigm(float x) { return 1.f / (1.f + __expf(-x)); }
__device__ __forceinline__ float tanh_(float x) {
    x = fminf(fmaxf(x, -15.f), 15.f);
    float e = __expf(2.f * x);
    return (e - 1.f) / (e + 1.f);
}

// two-level grid barrier: per-block flag stores (64B apart) + single epoch word.
// RELAXED polls (no cache-invalidate) with periodic/final ACQUIRE for ordering.
__device__ __forceinline__ void gbar(int* sync, int gen, int blk) {
    __syncthreads();   // drains all waves' vmem (compiler emits vmcnt(0) before s_barrier)
    int* epoch = sync;
    if (blk == 0) {
        const int t = threadIdx.x;
        int done = (t == 0 || t >= NBLK) ? 1 : 0;
        int* myarr = sync + 256 + t * 16;
        int it = 0;
        for (;;) {
            if (!done) {
                int v = ((it & 15) == 15)
                    ? __hip_atomic_load(myarr, __ATOMIC_ACQUIRE, __HIP_MEMORY_SCOPE_AGENT)
                    : __hip_atomic_load(myarr, __ATOMIC_RELAXED, __HIP_MEMORY_SCOPE_AGENT);
                done = (v >= gen);
            }
            ++it;
            if (__syncthreads_and(done)) break;
            __builtin_amdgcn_s_sleep(1);
        }
        if (t == 0) {
            (void)__hip_atomic_load(sync + 256 + 16, __ATOMIC_ACQUIRE, __HIP_MEMORY_SCOPE_AGENT);
            __hip_atomic_store(epoch, gen, __ATOMIC_RELEASE, __HIP_MEMORY_SCOPE_AGENT);
        }
        __syncthreads();
    } else {
        if (threadIdx.x == 0) {
            __hip_atomic_store(sync + 256 + blk * 16, gen, __ATOMIC_RELEASE, __HIP_MEMORY_SCOPE_AGENT);
            int it = 0;
            for (;;) {
                int v = ((it & 15) == 15)
                    ? __hip_atomic_load(epoch, __ATOMIC_ACQUIRE, __HIP_MEMORY_SCOPE_AGENT)
                    : __hip_atomic_load(epoch, __ATOMIC_RELAXED, __HIP_MEMORY_SCOPE_AGENT);
                ++it;
                if (v >= gen) break;
                __builtin_amdgcn_s_sleep(1);
            }
            (void)__hip_atomic_load(epoch, __ATOMIC_ACQUIRE, __HIP_MEMORY_SCOPE_AGENT);
        }
        __syncthreads();
    }
}

// gates GEMM: 64 x 24 slice, K=1024 ([u0;u1]) with hi/lo 3-term. A=ublob, W=LDS combined.
__device__ __forceinline__ void gates_task(
    const u16* __restrict__ ublob, const u16* s_wc, const float* s_gb,
    float* __restrict__ bc, int blk, int task, int lr, int lq)
{
    const int ct = task & 1, rt = task >> 1;
    const int cc = ct * 8 + lr;
    const int col = blk * GCOLS + cc;
    const u16* wcol = s_wc + cc * WCS;
    const u16* arow = ublob + (size_t)(rt * 16 + lr) * 2048;
    f32x4 acc = {0.f, 0.f, 0.f, 0.f};
    #pragma unroll 4
    for (int c = 0; c < 16; ++c) {
        int kk = c * 32 + lq * 8;
        bf16x8 ah = *(const bf16x8*)(arow + kk);
        bf16x8 al = *(const bf16x8*)(arow + 512 + kk);
        bf16x8 wh = *(const bf16x8*)(wcol + kk);
        bf16x8 wl = *(const bf16x8*)(wcol + 1024 + kk);
        acc = MFMA16(ah, wh, acc); acc = MFMA16(al, wh, acc); acc = MFMA16(ah, wl, acc);
    }
    #pragma unroll 4
    for (int c = 0; c < 16; ++c) {
        int kk = c * 32 + lq * 8;
        bf16x8 ah = *(const bf16x8*)(arow + 1024 + kk);
        bf16x8 al = *(const bf16x8*)(arow + 1536 + kk);
        bf16x8 wh = *(const bf16x8*)(wcol + 512 + kk);
        bf16x8 wl = *(const bf16x8*)(wcol + 1536 + kk);
        acc = MFMA16(ah, wh, acc); acc = MFMA16(al, wh, acc); acc = MFMA16(ah, wl, acc);
    }
    float bias = s_gb[cc];
    #pragma unroll
    for (int r = 0; r < 4; ++r)
        bc[(size_t)(rt * 16 + lq * 4 + r) * BCS + 512 + col] = acc[r] + bias;
}

// x-gates GEMM for row i: 64 x 24 slice, K=512 hi/lo 3-term. A=featblob row i, W=LDS.
__device__ __forceinline__ void x_task(
    int i, const u16* __restrict__ featblob, const u16* s_wxw, const float* s_xb,
    float* __restrict__ bc, int blk, int task, int lr, int lq)
{
    const int ct = task & 1, rt = task >> 1;
    const int cc = ct * 8 + lr;
    const int col = blk * GCOLS + cc;
    const u16* wcol = s_wxw + cc * WXS;
    const u16* arow = featblob + (size_t)(i * 64 + rt * 16 + lr) * 1024;
    f32x4 acc = {0.f, 0.f, 0.f, 0.f};
    #pragma unroll 4
    for (int c = 0; c < 16; ++c) {
        int kk = c * 32 + lq * 8;
        bf16x8 ah = *(const bf16x8*)(arow + kk);
        bf16x8 al = *(const bf16x8*)(arow + 512 + kk);
        bf16x8 wh = *(const bf16x8*)(wcol + kk);
        bf16x8 wl = *(const bf16x8*)(wcol + 512 + kk);
        acc = MFMA16(ah, wh, acc); acc = MFMA16(al, wh, acc); acc = MFMA16(ah, wl, acc);
    }
    float bias = s_xb[cc];
    #pragma unroll
    for (int r = 0; r < 4; ++r)
        bc[(size_t)(rt * 16 + lq * 4 + r) * BCS + 3584 + col] = acc[r] + bias;
}

// M GEMM: 16x16 tile per block (ct=blk>>2, rt=blk&3), K=512 per Wr pair, W streamed.
__device__ __forceinline__ void m_task(
    const u16* __restrict__ ublob, const u16* __restrict__ WrB,
    float* __restrict__ bc, int blk, int lr, int lq)
{
    const int ct = blk >> 2, rt = blk & 3;
    const int col = ct * 16 + lr;
    const u16* wcol = WrB + (size_t)col * 2048;
    const u16* arow = ublob + (size_t)(rt * 16 + lr) * 2048;
    f32x4 acc = {0.f, 0.f, 0.f, 0.f};
    #pragma unroll 4
    for (int c = 0; c < 16; ++c) {
        int kk = c * 32 + lq * 8;
        bf16x8 a0h = *(const bf16x8*)(arow + kk);
        bf16x8 a0l = *(const bf16x8*)(arow + 512 + kk);
        bf16x8 a1h = *(const bf16x8*)(arow + 1024 + kk);
        bf16x8 a1l = *(const bf16x8*)(arow + 1536 + kk);
        bf16x8 w0h = *(const bf16x8*)(wcol + kk);
        bf16x8 w0l = *(const bf16x8*)(wcol + 512 + kk);
        bf16x8 w1h = *(const bf16x8*)(wcol + 1024 + kk);
        bf16x8 w1l = *(const bf16x8*)(wcol + 1536 + kk);
        acc = MFMA16(a0h, w0h, acc); acc = MFMA16(a0l, w0h, acc); acc = MFMA16(a0h, w0l, acc);
        acc = MFMA16(a1h, w1h, acc); acc = MFMA16(a1l, w1h, acc); acc = MFMA16(a1h, w1l, acc);
    }
    #pragma unroll
    for (int r = 0; r < 4; ++r)
        bc[(size_t)(rt * 16 + lq * 4 + r) * BCS + col] = acc[r];
}

__global__ __launch_bounds__(NTHR) void grn_kernel(
    const float* __restrict__ feat, const float* __restrict__ Wi_c, const float* __restrict__ Wh_c,
    const float* __restrict__ bi_c, const float* __restrict__ bh_c,
    const float* __restrict__ Wi_p, const float* __restrict__ Wh_p,
    const float* __restrict__ bi_p, const float* __restrict__ bh_p,
    const float* __restrict__ lin_w, const float* __restrict__ lin_b,
    const float* __restrict__ Wr0, const float* __restrict__ Wr1,
    const int* __restrict__ adj, const int* __restrict__ smask,
    float* __restrict__ out,
    float* __restrict__ H, float* __restrict__ q, u16* __restrict__ ublob,
    u16* __restrict__ featblob, float* __restrict__ bc, u16* __restrict__ WrB,
    int* __restrict__ sync)
{
    const int t = threadIdx.x, blk = blockIdx.x;
    const int lane = t & 63, wv = t >> 6;
    const int lr = lane & 15, lq = lane >> 4;
    int gen = 0;

    __shared__ u16 s_wc[GCOLS * WCS];                       // 98688 B
    __shared__ __align__(16) char s_wx_raw[GCOLS * WXS * 2]; // 49536 B (x-weights / Wg staging)
    __shared__ float s_u0[DD];
    __shared__ float s_ut[DD];
    __shared__ float s_red[NTHR];
    __shared__ float s_hk[NN];
    __shared__ float s_q[NN];
    __shared__ float s_w[NN];
    __shared__ float s_ws[NN];
    __shared__ float s_gb[GCOLS];
    __shared__ float s_xb[GCOLS];

    u16* s_wxw = (u16*)s_wx_raw;
    float* s_wgf = (float*)s_wx_raw;

    const float wkreg = lin_w[DD + t];

    // ================= Ph0: prologue =================
    // featblob[(n*64+b)] = hi/lo of feat[b,n,:]
    for (int rr = 0; rr < 64; ++rr) {
        int gr = blk * 64 + rr;
        int bb_ = gr >> 7, nn_ = gr & 127;
        float x = feat[(size_t)gr * DD + t];
        u16 h = f2b(x);
        u16* dst = featblob + (size_t)(nn_ * 64 + bb_) * 1024;
        dst[t] = h;
        dst[512 + t] = f2b(x - b2f(h));
    }
    // WrB: 512 cols x [W0h|W0l|W1h|W1l]
    for (int cc = 0; cc < 4; ++cc) {
        int c = blk * 4 + cc;
        float w0 = Wr0[(size_t)c * DD + t], w1 = Wr1[(size_t)c * DD + t];
        u16 h0 = f2b(w0), h1 = f2b(w1);
        u16* dst = WrB + (size_t)c * 2048;
        dst[t] = h0; dst[512 + t] = f2b(w0 - b2f(h0));
        dst[1024 + t] = h1; dst[1536 + t] = f2b(w1 - b2f(h1));
    }
    // q[b,n] = feat.wq + lin_b
    {
        float linb = lin_b[0];
        float wqf[8];
        #pragma unroll
        for (int jj = 0; jj < 8; ++jj) wqf[jj] = lin_w[lane * 8 + jj];
        for (int rr = 0; rr < 8; ++rr) {
            int row = blk * 64 + wv * 8 + rr;
            const float* fp = feat + (size_t)row * DD + lane * 8;
            float p = 0.f;
            #pragma unroll
            for (int jj = 0; jj < 8; ++jj) p += fp[jj] * wqf[jj];
            #pragma unroll
            for (int off = 32; off; off >>= 1) p += __shfl_down(p, off, 64);
            if (lane == 0) q[row] = p + linb;
        }
    }
    // stage this block's 24 Wg rows (Wh_c|Wi_p) as s_wgf[j][cc]; biases
    {
        int jg0 = blk * GCOLS;
        for (int cc = 0; cc < GCOLS; ++cc) {
            int jg = jg0 + cc;
            const float* src = (jg < 1536) ? (Wh_c + (size_t)jg * DD) : (Wi_p + (size_t)(jg - 1536) * DD);
            s_wgf[t * GCOLS + cc] = src[t];
        }
        if (t < GCOLS) {
            int jg = jg0 + t;
            s_gb[t] = (jg < 1536) ? bh_c[jg] : bi_p[jg - 1536];
            s_xb[t] = (jg < 1536) ? bi_c[jg] : bh_p[jg - 1536];
        }
    }
    __syncthreads();
    // Wcomb[k, jg] = sum_j Wr{0,1}[j,k] * Wg[jg,j]  (fp32), hi/lo into s_wc
    {
        float acc0[GCOLS], acc1[GCOLS];
        #pragma unroll
        for (int cc = 0; cc < GCOLS; ++cc) { acc0[cc] = 0.f; acc1[cc] = 0.f; }
        for (int j = 0; j < DD; ++j) {
            float wr0 = Wr0[(size_t)j * DD + t];
            float wr1 = Wr1[(size_t)j * DD + t];
            const float* g = s_wgf + j * GCOLS;
            #pragma unroll
            for (int cc = 0; cc < GCOLS; ++cc) {
                float gv = g[cc];
                acc0[cc] += wr0 * gv;
                acc1[cc] += wr1 * gv;
            }
        }
        __syncthreads();   // done with s_wgf staging
        #pragma unroll
        for (int cc = 0; cc < GCOLS; ++cc) {
            u16 h0 = f2b(acc0[cc]);
            s_wc[cc * WCS + t] = h0;
            s_wc[cc * WCS + 1024 + t] = f2b(acc0[cc] - b2f(h0));
            u16 h1 = f2b(acc1[cc]);
            s_wc[cc * WCS + 512 + t] = h1;
            s_wc[cc * WCS + 1536 + t] = f2b(acc1[cc] - b2f(h1));
        }
    }
    // x-weights hi/lo into s_wxw (overwrites staging)
    {
        int jx0 = blk * GCOLS;
        for (int cc = 0; cc < GCOLS; ++cc) {
            int jx = jx0 + cc;
            const float* src = (jx < 1536) ? (Wi_c + (size_t)jx * DD) : (Wh_p + (size_t)(jx - 1536) * DD);
            float w = src[t];
            u16 h = f2b(w);
            s_wxw[cc * WXS + t] = h;
            s_wxw[cc * WXS + 512 + t] = f2b(w - b2f(h));
        }
    }
    gbar(sync, ++gen, blk);

    // ================= Ph0x: x-gates row 0; load s_q =================
    x_task(0, featblob, s_wxw, s_xb, bc, blk, wv, lr, lq);
    if (blk < BB && t < NN) s_q[t] = q[blk * NN + t];
    gbar(sync, ++gen, blk);

    // ================= Ph1: row 0 init =================
    if (blk < BB) {
        const float* bcb = bc + (size_t)blk * BCS;
        float ir = bcb[3584 + t], iz = bcb[4096 + t], inn = bcb[4608 + t];
        float r = sigm(ir + bh_c[t]), z = sigm(iz + bh_c[512 + t]);
        float C = (1.f - z) * tanh_(inn + r * bh_c[1024 + t]);
        float ghr = bcb[5120 + t], ghz = bcb[5632 + t], ghn = bcb[6144 + t];
        float r2 = sigm(bi_p[t] + ghr), z2 = sigm(bi_p[512 + t] + ghz);
        float n2 = tanh_(bi_p[1024 + t] + r2 * ghn);
        float x = feat[(size_t)(blk * NN) * DD + t];
        float P = (1.f - z2) * n2 + z2 * x;
        float Hv = C + P;
        H[(size_t)(blk * NN) * DD + t] = Hv;
        out[(size_t)(blk * NN) * DD + t] = Hv;
        s_red[t] = Hv * wkreg;
        __syncthreads();
        if (wv == 0) {
            float p = 0.f;
            #pragma unroll
            for (int jj = 0; jj < 8; ++jj) p += s_red[lane + 64 * jj];
            #pragma unroll
            for (int off = 32; off; off >>= 1) p += __shfl_down(p, off, 64);
            if (lane == 0) s_hk[0] = p;
        }
    }
    gbar(sync, ++gen, blk);

    // ================= main scan =================
    for (int i = 1; i < NN; ++i) {
        // ---- PhA (blocks 0..63): finish row i-1, softmax, H-scan -> ublob ----
        if (blk < BB) {
            int va0 = 0, va1 = 0, vs0 = 0, vs1 = 0;
            float qv = 0.f;
            if (wv == 0) {
                const int* ar_ = adj + (size_t)(blk * NN + i) * NN;
                const int* sr_ = smask + (size_t)(blk * NN + i) * NN;
                va0 = ar_[lane]; va1 = ar_[lane + 64];
                vs0 = sr_[lane]; vs1 = sr_[lane + 64];
                qv = s_q[i];
            }
            if (i >= 2) {
                int j = i - 1;
                const float* bcb = bc + (size_t)blk * BCS;
                float Mv = bcb[t];
                float hr = bcb[512 + t], hz = bcb[1024 + t], hn = bcb[1536 + t];
                float gir = bcb[2048 + t], giz = bcb[2560 + t], gin = bcb[3072 + t];
                float ir = bcb[3584 + t], iz = bcb[4096 + t], inn = bcb[4608 + t];
                float ghr = bcb[5120 + t], ghz = bcb[5632 + t], ghn = bcb[6144 + t];
                float x = feat[(size_t)(blk * NN + j) * DD + t];
                float r = sigm(ir + hr), z = sigm(iz + hz);
                float C = (1.f - z) * tanh_(inn + r * hn) + z * Mv;
                float r2 = sigm(gir + ghr), z2 = sigm(giz + ghz);
                float P = (1.f - z2) * tanh_(gin + r2 * ghn) + z2 * x;
                float Hv = C + P;
                H[(size_t)(blk * NN + j) * DD + t] = Hv;
                out[(size_t)(blk * NN + j) * DD + t] = Hv;
                s_red[t] = Hv * wkreg;
            }
            s_u0[t] = 0.f; s_ut[t] = 0.f;
            __syncthreads();
            if (wv == 0) {
                if (i >= 2) {
                    float p = 0.f;
                    #pragma unroll
                    for (int jj = 0; jj < 8; ++jj) p += s_red[lane + 64 * jj];
                    #pragma unroll
                    for (int off = 32; off; off >>= 1) p += __shfl_down(p, off, 64);
                    if (lane == 0) s_hk[i - 1] = p;
                }
                int n2i = lane + 64;
                float a0 = (lane < i && va0 != 0) ? (qv + s_hk[lane]) : -1e30f;
                float a1 = (n2i < i && va1 != 0) ? (qv + s_hk[n2i]) : -1e30f;
                float m = fmaxf(a0, a1);
                #pragma unroll
                for (int off = 32; off; off >>= 1) m = fmaxf(m, __shfl_xor(m, off, 64));
                float e0 = (a0 > -1e29f) ? __expf(a0 - m) : 0.f;
                float e1 = (a1 > -1e29f) ? __expf(a1 - m) : 0.f;
                float ss = e0 + e1;
                #pragma unroll
                for (int off = 32; off; off >>= 1) ss += __shfl_xor(ss, off, 64);
                float inv = 1.f / ss;
                float w0 = e0 * inv, w1 = e1 * inv;
                s_w[lane] = w0; s_w[n2i] = w1;
                s_ws[lane] = w0 * (float)vs0;
                s_ws[n2i] = w1 * (float)vs1;
            }
            __syncthreads();
            // H-scan: 4 row-groups x 128 dim-quads, f32x4, unroll for MLP
            {
                int g = t >> 7, dqb = (t & 127) * 4;
                const float* Hb = H + (size_t)blk * NN * DD + dqb;
                f32x4 u0 = {0.f, 0.f, 0.f, 0.f}, ut = {0.f, 0.f, 0.f, 0.f};
                int n = g;
                for (; n + 12 < i; n += 16) {
                    f32x4 h0 = *(const f32x4*)(Hb + (size_t)n * DD);
                    f32x4 h1 = *(const f32x4*)(Hb + (size_t)(n + 4) * DD);
                    f32x4 h2 = *(const f32x4*)(Hb + (size_t)(n + 8) * DD);
                    f32x4 h3 = *(const f32x4*)(Hb + (size_t)(n + 12) * DD);
                    u0 += s_ws[n] * h0 + s_ws[n + 4] * h1 + s_ws[n + 8] * h2 + s_ws[n + 12] * h3;
                    ut += s_w[n] * h0 + s_w[n + 4] * h1 + s_w[n + 8] * h2 + s_w[n + 12] * h3;
                }
                for (; n < i; n += 4) {
                    f32x4 h0 = *(const f32x4*)(Hb + (size_t)n * DD);
                    u0 += s_ws[n] * h0;
                    ut += s_w[n] * h0;
                }
                #pragma unroll
                for (int e = 0; e < 4; ++e) {
                    atomicAdd(&s_u0[dqb + e], u0[e]);
                    atomicAdd(&s_ut[dqb + e], ut[e]);
                }
            }
            __syncthreads();
            {
                float U0 = s_u0[t];
                float U1 = s_ut[t] - U0;
                u16* ub = ublob + (size_t)blk * 2048;
                u16 h0 = f2b(U0);
                ub[t] = h0; ub[512 + t] = f2b(U0 - b2f(h0));
                u16 h1 = f2b(U1);
                ub[1024 + t] = h1; ub[1536 + t] = f2b(U1 - b2f(h1));
            }
        }
        gbar(sync, ++gen, blk);

        // ---- PhB: combined gates + x-gates(row i) + M, one phase ----
        gates_task(ublob, s_wc, s_gb, bc, blk, wv, lr, lq);
        if (wv == 6) {
            x_task(i, featblob, s_wxw, s_xb, bc, blk, 6, lr, lq);
            x_task(i, featblob, s_wxw, s_xb, bc, blk, 7, lr, lq);
        } else if (wv == 7) {
            m_task(ublob, WrB, bc, blk, lr, lq);
        } else {
            x_task(i, featblob, s_wxw, s_xb, bc, blk, wv, lr, lq);
        }
        gbar(sync, ++gen, blk);
    }

    // ---- final: row 127 ----
    if (blk < BB) {
        int j = NN - 1;
        const float* bcb = bc + (size_t)blk * BCS;
        float Mv = bcb[t];
        float hr = bcb[512 + t], hz = bcb[1024 + t], hn = bcb[1536 + t];
        float gir = bcb[2048 + t], giz = bcb[2560 + t], gin = bcb[3072 + t];
        float ir = bcb[3584 + t], iz = bcb[4096 + t], inn = bcb[4608 + t];
        float ghr = bcb[5120 + t], ghz = bcb[5632 + t], ghn = bcb[6144 + t];
        float x = feat[(size_t)(blk * NN + j) * DD + t];
        float r = sigm(ir + hr), z = sigm(iz + hz);
        float C = (1.f - z) * tanh_(inn + r * hn) + z * Mv;
        float r2 = sigm(gir + ghr), z2 = sigm(giz + ghz);
        float P = (1.f - z2) * tanh_(gin + r2 * ghn) + z2 * x;
        float Hv = C + P;
        H[(size_t)(blk * NN + j) * DD + t] = Hv;
        out[(size_t)(blk * NN + j) * DD + t] = Hv;
    }
}

extern "C" void kernel_launch(void* const* d_in, const int* in_sizes, int n_in,
                              void* d_out, int out_size, void* d_ws, size_t ws_size,
                              hipStream_t stream) {
    (void)in_sizes; (void)n_in; (void)out_size; (void)ws_size;
    const float* feat = (const float*)d_in[0];
    const float* Wi_c = (const float*)d_in[1];
    const float* Wh_c = (const float*)d_in[2];
    const float* bi_c = (const float*)d_in[3];
    const float* bh_c = (const float*)d_in[4];
    const float* Wi_p = (const float*)d_in[5];
    const float* Wh_p = (const float*)d_in[6];
    const float* bi_p = (const float*)d_in[7];
    const float* bh_p = (const float*)d_in[8];
    const float* lin_w = (const float*)d_in[9];
    const float* lin_b = (const float*)d_in[10];
    const float* Wr0 = (const float*)d_in[11];
    const float* Wr1 = (const float*)d_in[12];
    const int* adj = (const int*)d_in[13];
    const int* smask = (const int*)d_in[14];
    float* out = (float*)d_out;

    char* ws = (char*)d_ws;
    size_t off = 0;
    int* sync_ = (int*)(ws + off);      off += 16384;
    float* H = (float*)(ws + off);      off += (size_t)BB * NN * DD * 4;      // 16.8 MB
    float* q = (float*)(ws + off);      off += (size_t)BB * NN * 4;           // 32 KB
    u16* ublob = (u16*)(ws + off);      off += (size_t)BB * 2048 * 2;         // 256 KB
    u16* featblob = (u16*)(ws + off);   off += (size_t)BB * NN * 1024 * 2;    // 16.8 MB
    float* bc = (float*)(ws + off);     off += (size_t)BB * BCS * 4;          // 1.7 MB
    u16* WrB = (u16*)(ws + off);        off += (size_t)512 * 2048 * 2;        // 2 MB

    (void)hipMemsetAsync(d_ws, 0, 16384, stream);   // reset barrier flags + epoch
    hipLaunchKernelGGL(grn_kernel, dim3(NBLK), dim3(NTHR), 0, stream,
                       feat, Wi_c, Wh_c, bi_c, bh_c, Wi_p, Wh_p, bi_p, bh_p,
                       lin_w, lin_b, Wr0, Wr1, adj, smask, out,
                       H, q, ublob, featblob, bc, WrB, sync_);
}